// Round 8
// baseline (248.459 us; speedup 1.0000x reference)
//
#include <hip/hip_runtime.h>

// emb lookup -> RNN tanh(xp_t + h @ W_hh^T) over S=128 -> 5-class head.
// B=4096, S=128, D=256, VOCAB=50000. Floats f32, x int32, out f32.
//
// Phase 0: P[v] = bf16(emb[v] @ W_ih^T + b_ih + b_hh) — project the 50k TABLE.
// Phase 1: 256 blocks x 16 rows x 512 thr. W_hh bf16 B-frags in VGPRs; h in
//   granule-XOR-swizzled LDS (conflict-free writes), double-buffered.
//   xp gather = ONE global_load_lds DMA per wave per step (16B/lane, half-wave per
//   table row) instead of 64 scalar u16 loads (R4-R6 were invariant at 130us: the
//   scattered-gather VMEM machinery re-exposed its latency at every barrier).
//   R8 FIX: in-loop DMA dest now includes the per-wave offset (+wid*1024) — R7
//   dropped it, so all 8 waves clobbered rows 0-1 and rows 2-15 read stale xp.

typedef __attribute__((ext_vector_type(8))) short bf16x8;   // 8 bf16 = 4 VGPRs
typedef __attribute__((ext_vector_type(4))) float f32x4;    // MFMA 16x16 accumulator

#define VOCAB 50000
#define NBLK_EMB 256
#define LDS_STRIDE 264   // emb kernel staging only

__device__ __align__(256) unsigned short g_P[VOCAB * 256];  // 25.6 MB projected table

static __device__ __forceinline__ float bf2f(unsigned short u) {
    union { unsigned int i; float f; } v; v.i = ((unsigned int)u) << 16; return v.f;
}
static __device__ __forceinline__ unsigned short f2bf_rne(float f) {
    union { float f; unsigned int i; } v; v.f = f;
    unsigned int r = v.i + 0x7FFFu + ((v.i >> 16) & 1u);
    return (unsigned short)(r >> 16);
}
static __device__ __forceinline__ unsigned short f2bf_fast(float f) {   // round-half-up
    union { float f; unsigned int i; } v; v.f = f;
    return (unsigned short)((v.i + 0x8000u) >> 16);
}
static __device__ __forceinline__ bf16x8 cvt8(float4 a, float4 b) {
    bf16x8 r;
    r[0] = (short)f2bf_rne(a.x); r[1] = (short)f2bf_rne(a.y);
    r[2] = (short)f2bf_rne(a.z); r[3] = (short)f2bf_rne(a.w);
    r[4] = (short)f2bf_rne(b.x); r[5] = (short)f2bf_rne(b.y);
    r[6] = (short)f2bf_rne(b.z); r[7] = (short)f2bf_rne(b.w);
    return r;
}
static __device__ __forceinline__ bf16x8 load8_bf(const float* __restrict__ p) {
    return cvt8(((const float4*)p)[0], ((const float4*)p)[1]);
}
static __device__ __forceinline__ float fast_tanh(float x) {
    x = __builtin_amdgcn_fmed3f(x, -8.f, 8.f);
    float e = __expf(2.f * x);
    return __builtin_fmaf(-2.f, __builtin_amdgcn_rcpf(e + 1.f), 1.f);
}
// async global->LDS, 16 B per lane; lds dest is wave-uniform base + lane*16
static __device__ __forceinline__ void dma16(const void* g, void* l) {
    __builtin_amdgcn_global_load_lds(
        (const __attribute__((address_space(1))) unsigned int*)g,
        (__attribute__((address_space(3))) unsigned int*)l, 16, 0, 0);
}
static __device__ __forceinline__ void wait_vm0() {
    __builtin_amdgcn_s_waitcnt(0x0f70);   // vmcnt(0), lgkm/exp no-wait
}

// ---------------- Phase 0: P = bf16(emb @ W_ih^T + (b_ih + b_hh)) ----------------
__global__ __launch_bounds__(256)
void emb_proj_kernel(const float* __restrict__ emb,
                     const float* __restrict__ W_ih,
                     const float* __restrict__ b_ih,
                     const float* __restrict__ b_hh)
{
    __shared__ __align__(16) unsigned short tin [16 * LDS_STRIDE];
    __shared__ __align__(16) unsigned short tout[16 * LDS_STRIDE];
    const int tid  = threadIdx.x;
    const int lane = tid & 63;
    const int wid  = tid >> 6;
    const int n0   = wid * 64;
    const int row  = tid >> 4, seg = tid & 15;

    bf16x8 wf[4][8];
    float  bias[4];
    #pragma unroll
    for (int nt = 0; nt < 4; ++nt) {
        int n = n0 + nt * 16 + (lane & 15);
        bias[nt] = b_ih[n] + b_hh[n];
        #pragma unroll
        for (int kt = 0; kt < 8; ++kt)
            wf[nt][kt] = load8_bf(W_ih + n * 256 + (lane >> 4) * 8 + kt * 32);
    }

    int tile = blockIdx.x;
    float4 a0, a1, a2, a3;
    {
        const float4* s = (const float4*)(emb + ((size_t)tile * 16 + row) * 256 + seg * 16);
        a0 = s[0]; a1 = s[1]; a2 = s[2]; a3 = s[3];
    }

    for (; tile < 3125; tile += NBLK_EMB) {
        *(bf16x8*)(&tin[row * LDS_STRIDE + seg * 16])     = cvt8(a0, a1);
        *(bf16x8*)(&tin[row * LDS_STRIDE + seg * 16 + 8]) = cvt8(a2, a3);
        int tn = tile + NBLK_EMB;
        if (tn < 3125) {
            const float4* s = (const float4*)(emb + ((size_t)tn * 16 + row) * 256 + seg * 16);
            a0 = s[0]; a1 = s[1]; a2 = s[2]; a3 = s[3];
        }
        __syncthreads();   // B1: tin visible

        f32x4 acc[4];
        #pragma unroll
        for (int nt = 0; nt < 4; ++nt) acc[nt] = (f32x4){0.f, 0.f, 0.f, 0.f};
        #pragma unroll
        for (int kt = 0; kt < 8; ++kt) {
            bf16x8 a = *(bf16x8*)(&tin[(lane & 15) * LDS_STRIDE + (lane >> 4) * 8 + kt * 32]);
            #pragma unroll
            for (int nt = 0; nt < 4; ++nt)
                acc[nt] = __builtin_amdgcn_mfma_f32_16x16x32_bf16(a, wf[nt][kt], acc[nt], 0, 0, 0);
        }
        #pragma unroll
        for (int nt = 0; nt < 4; ++nt) {
            int n = n0 + nt * 16 + (lane & 15);
            #pragma unroll
            for (int r = 0; r < 4; ++r)
                tout[((lane >> 4) * 4 + r) * LDS_STRIDE + n] = f2bf_rne(acc[nt][r] + bias[nt]);
        }
        __syncthreads();   // B2: tout complete, tin reads complete
        {
            uint4 o0 = *(uint4*)(&tout[row * LDS_STRIDE + seg * 16]);
            uint4 o1 = *(uint4*)(&tout[row * LDS_STRIDE + seg * 16 + 8]);
            uint4* dst = (uint4*)(g_P + ((size_t)tile * 16 + row) * 256 + seg * 16);
            dst[0] = o0; dst[1] = o1;
        }
    }
}

// ---------------- Phase 1: recurrence + classifier ----------------
// h LDS layout (per 8KB buffer): (row m, col c) at byte m*512 + (((c>>3)^m)<<4) + (c&7)*2.
// xp LDS layout (per 8KB buffer, DMA-written): wave w owns rows 2w,2w+1 at w*1024:
//   (row r, col c) at byte (r>>1)*1024 + (r&1)*512 + ((((c>>3)+(r>>1))&31)<<4) + (c&7)*2
//   (granule rotation by r>>1 makes the C-layout epilogue reads conflict-free).
__global__ __launch_bounds__(512, 2)
void rnn_kernel(const int* __restrict__ x,
                const float* __restrict__ W_hh,
                const float* __restrict__ W_cls,
                const float* __restrict__ b_cls,
                float* __restrict__ out)
{
    __shared__ __align__(16) unsigned short h_lds [2][16 * 256];  // 2 x 8 KB
    __shared__ __align__(16) unsigned short xp_lds[2][16 * 256];  // 2 x 8 KB
    __shared__ __align__(16) int tok_t[128 * 16];                 // [t][row]
    __shared__ __align__(16) float wcls_lds[5 * 256];
    __shared__ float bcls_lds[5];

    const int tid  = threadIdx.x;
    const int lane = tid & 63;
    const int wid  = tid >> 6;          // 8 waves
    const int b0   = blockIdx.x * 16;
    const int n0   = wid * 32;          // wave's 32-col slice
    const int l15  = lane & 15;
    const int quad = lane >> 4;

    // W_hh -> bf16 B-fragments, VGPR-resident
    bf16x8 wf[2][8];
    #pragma unroll
    for (int nt = 0; nt < 2; ++nt) {
        int n = n0 + nt * 16 + l15;
        #pragma unroll
        for (int kt = 0; kt < 8; ++kt)
            wf[nt][kt] = load8_bf(W_hh + n * 256 + quad * 8 + kt * 32);
    }

    // stage tokens transposed: tok_t[t*16 + row]
    {
        int row = tid & 15, tq = tid >> 4;   // tq 0..31
        int4 v = *(const int4*)(x + (size_t)(b0 + row) * 128 + tq * 4);
        tok_t[(tq * 4 + 0) * 16 + row] = v.x;
        tok_t[(tq * 4 + 1) * 16 + row] = v.y;
        tok_t[(tq * 4 + 2) * 16 + row] = v.z;
        tok_t[(tq * 4 + 3) * 16 + row] = v.w;
    }
    if (tid < 320) ((float4*)wcls_lds)[tid] = ((const float4*)W_cls)[tid];
    if (tid < 5)   bcls_lds[tid] = b_cls[tid];
    #pragma unroll
    for (int i = 0; i < 4; ++i) ((unsigned int*)h_lds[0])[tid + i * 512] = 0;

    // precomputed loop-invariant LDS byte offsets (buf1 = +8192 imm)
    int aoff[8];   // A-frag reads from swizzled h
    #pragma unroll
    for (int kt = 0; kt < 8; ++kt)
        aoff[kt] = l15 * 512 + (((quad + 4 * kt) ^ l15) << 4);
    int woff[8];   // h writes (C-layout), conflict-free
    #pragma unroll
    for (int nt = 0; nt < 2; ++nt)
        #pragma unroll
        for (int r = 0; r < 4; ++r) {
            int row = quad * 4 + r;
            int g   = (n0 >> 3) + nt * 2 + (l15 >> 3);
            woff[nt * 4 + r] = row * 512 + ((g ^ row) << 4) + (l15 & 7) * 2;
        }
    int xoff[8];   // xp reads (C-layout) from rotated DMA layout, conflict-free
    #pragma unroll
    for (int nt = 0; nt < 2; ++nt)
        #pragma unroll
        for (int r = 0; r < 4; ++r) {
            int row = quad * 4 + r, c = n0 + nt * 16 + l15;
            xoff[nt * 4 + r] = (row >> 1) * 1024 + (row & 1) * 512
                             + ((((c >> 3) + (row >> 1)) & 31) << 4) + (c & 7) * 2;
        }

    // DMA lane mapping: wave w fetches rows 2w,2w+1; lane reads global segment
    // ((lane&31) - w) & 31 so that lds granule G holds segment (G - w) & 31.
    const int dmarow = 2 * wid + (lane >> 5);
    const unsigned int dmaseg = (unsigned int)(((lane & 31) - wid) & 31);
    char* const xbase = (char*)&xp_lds[0][0];
    const int   wofs  = wid << 10;       // per-wave region offset (THE R7 bug: was dropped)

    __syncthreads();   // tok_t, wcls, h=0 visible
    {
        int tok = tok_t[0 * 16 + dmarow];
        dma16(g_P + (size_t)tok * 256 + dmaseg * 8, xbase + wofs);
    }
    wait_vm0();
    __syncthreads();   // xp(0) landed in buf0

    char* const h0 = (char*)&h_lds[0][0];

    auto step = [&](const char* hA, char* hW, const char* xR, char* gw, int t) {
        // issue next step's DMA first (drains at this step's end barrier)
        if (t + 1 < 128) {
            int tok = tok_t[(t + 1) * 16 + dmarow];
            dma16(g_P + (size_t)tok * 256 + dmaseg * 8, gw + wofs);
        }
        // acc init = xp (MFMA C operand adds it for free)
        f32x4 acc0, acc1;
        #pragma unroll
        for (int r = 0; r < 4; ++r) {
            acc0[r] = bf2f(*(const unsigned short*)(xR + xoff[r]));
            acc1[r] = bf2f(*(const unsigned short*)(xR + xoff[4 + r]));
        }
        #pragma unroll
        for (int kt = 0; kt < 8; ++kt) {
            bf16x8 a = *(const bf16x8*)(hA + aoff[kt]);
            acc0 = __builtin_amdgcn_mfma_f32_16x16x32_bf16(a, wf[0][kt], acc0, 0, 0, 0);
            acc1 = __builtin_amdgcn_mfma_f32_16x16x32_bf16(a, wf[1][kt], acc1, 0, 0, 0);
        }
        #pragma unroll
        for (int r = 0; r < 4; ++r) {
            *(unsigned short*)(hW + woff[r])     = f2bf_fast(fast_tanh(acc0[r]));
            *(unsigned short*)(hW + woff[4 + r]) = f2bf_fast(fast_tanh(acc1[r]));
        }
    };

    #pragma unroll 1
    for (int t2 = 0; t2 < 64; ++t2) {
        // even: h buf0 -> buf1; xp read buf0, DMA xp(t+1) into buf1
        step(h0,        h0 + 8192, xbase,        xbase + 8192, 2 * t2);
        wait_vm0();
        __syncthreads();
        // odd: h buf1 -> buf0; xp read buf1, DMA xp(t+1) into buf0
        step(h0 + 8192, h0,        xbase + 8192, xbase,        2 * t2 + 1);
        wait_vm0();
        __syncthreads();
    }

    // final h in buf0. Classifier: 4 threads per (row,c), shuffle-reduce.
    if (tid < 320) {
        int q = tid & 3, p = tid >> 2;
        int row = p / 5, c = p - row * 5;
        float acc = 0.f;
        #pragma unroll
        for (int kk = 0; kk < 64; ++kk) {
            int k = q * 64 + kk;
            int off = row * 512 + ((((k >> 3) ^ row)) << 4) + (k & 7) * 2;
            acc += bf2f(*(const unsigned short*)(h0 + off)) * wcls_lds[c * 256 + k];
        }
        acc += __shfl_xor(acc, 1);
        acc += __shfl_xor(acc, 2);
        if (q == 0) out[(size_t)(b0 + row) * 5 + c] = acc + bcls_lds[c];
    }
}

extern "C" void kernel_launch(void* const* d_in, const int* in_sizes, int n_in,
                              void* d_out, int out_size, void* d_ws, size_t ws_size,
                              hipStream_t stream)
{
    const int*   x     = (const int*)d_in[0];
    const float* emb   = (const float*)d_in[1];
    const float* W_ih  = (const float*)d_in[2];
    const float* W_hh  = (const float*)d_in[3];
    const float* b_ih  = (const float*)d_in[4];
    const float* b_hh  = (const float*)d_in[5];
    const float* W_cls = (const float*)d_in[6];
    const float* b_cls = (const float*)d_in[7];
    float*       out   = (float*)d_out;
    (void)d_ws; (void)ws_size;

    emb_proj_kernel<<<NBLK_EMB, 256, 0, stream>>>(emb, W_ih, b_ih, b_hh);
    rnn_kernel<<<256, 512, 0, stream>>>(x, W_hh, W_cls, b_cls, out);
}